// Round 10
// baseline (141.959 us; speedup 1.0000x reference)
//
#include <hip/hip_runtime.h>
#include <cstdint>

// Problem dims (fixed by the reference)
#define B_DIM 16
#define T_DIM 1024
#define DK    512     // D_IN
#define H_DIM 1024

// Tiling
#define TCH    128                 // t-rows per block (chunk)
#define NCH    (T_DIM / TCH)       // 8 chunks per (b,strip)
#define NB     128                 // output cols per block
#define NSTRIP (H_DIM / NB)        // 8 strips
#define NKT    16                  // k-tiles of BK=32

typedef __bf16 bf16x8 __attribute__((ext_vector_type(8)));
typedef __bf16 bf16x4 __attribute__((ext_vector_type(4)));
typedef float  f32x4  __attribute__((ext_vector_type(4)));

// ---- async global->LDS (16B per lane, wave-uniform LDS base + lane*16) ----
typedef __attribute__((address_space(1))) unsigned int* as1p;
typedef __attribute__((address_space(3))) unsigned int* as3p;

__device__ __forceinline__ void async_cp16(const void* g, void* l) {
  __builtin_amdgcn_global_load_lds((as1p)(uint64_t)g,
                                   (as3p)(uint32_t)(uint64_t)l, 16, 0, 0);
}

// ---- small prep: W cvt+transpose, meta, flag zero (x is NOT pre-processed) ----
// W: f32 [H][DK] -> bf16 k-major wbT[kq][h][8]
// grid = 512 (W) + 4 (meta) + 512 (flags) = 1028 blocks x 256 thr
__global__ __launch_bounds__(256) void prep(const float* __restrict__ W,
                                            __bf16* __restrict__ wbT,
                                            const float* __restrict__ raw_a,
                                            float4* __restrict__ meta,
                                            unsigned long long* __restrict__ flags) {
  const int bid = blockIdx.x, tid = threadIdx.x;
  if (bid < 512) {                        // W -> wbT[kq][h][8]
    const int i = bid * 256 + tid;        // i < 131072
    const int h  = i >> 7;                // DK/4 = 128 x4-chunks per row
    const int k0 = (i & 127) * 4;
    f32x4 v = ((const f32x4*)W)[i];
    bf16x4 o;
    o.x = (__bf16)v.x; o.y = (__bf16)v.y; o.z = (__bf16)v.z; o.w = (__bf16)v.w;
    *(bf16x4*)(wbT + ((size_t)(k0 >> 3) * H_DIM + h) * 8 + (k0 & 7)) = o;
  } else if (bid < 516) {                 // meta: {a, log2|a|, neg?, zero?}
    const int h = (bid - 512) * 256 + tid;
    const float a = tanhf(raw_a[h]);
    const float la2 = log2f(fabsf(a));
    meta[h] = make_float4(a, la2, (a < 0.f) ? 1.f : 0.f, (fabsf(a) < 1e-6f) ? 1.f : 0.f);
  } else {                                // lookback flags: zero 131072 u64
    flags[(bid - 516) * 256 + tid] = 0ULL;
  }
}

// ---- fused: GEMM (z = x W^T + b) + chunk-parallel weighted-cumsum scan ----
// A read DIRECTLY from f32 x (no pre-pass), reg-staged: thread (row=tid>>1,
// khalf=tid&1) loads 16 row-contiguous f32 (64B), cvt->bf16 off the MFMA
// path, 2x ds_write_b128 into As[kq][row ^ kq] — the 2-bit XOR swizzle makes
// BOTH the write phase ((row^kq)&7: 2 lanes/bank-quad) and the read phase
// ((c^q)&7: 2 lanes/bank-quad) conflict-FREE (2-way = free on CDNA4).
// B (pre-transposed bf16) via depth-3 global_load_lds (r3-proven).
// LDS = As 16 KB + Bs 24 KB = 40 KB -> 4 blocks/CU (16 waves: +33% TLP vs r3).
// 2-barrier/kt r3-proven skeleton; writeA(kt+1)'s register dependency forces
// the implicit drain of all older VMEM (incl. B(kt+1)) -> B(kt) is provably
// settled one full iteration before bar1(kt); explicit vmcnt(2) is
// belt-and-braces and stays correct under spills (extra VM ops only make the
// wait stricter).
// Grid: 1024 blocks; g = bid&127 (b = g>>3, chunk = g&7), strip = bid>>7 —
// proven mapping: bid%8 == chunk pins each (b,chunk) x-slice (256 KB f32) to
// one XCD's L2 (8 strip-blocks share it; HBM reads x once).  Lookback
// predecessors within 7 adjacent bids; 4 blocks/CU -> whole grid co-resident
// -> lookback deadlock-free under any dispatch order.
__global__ __launch_bounds__(256, 4) void fused_rnn(
    const float* __restrict__ xf,    // [B][T][DK] f32 (raw input)
    const __bf16* __restrict__ wbT,  // [64][H][8] k-major
    const float* __restrict__ bias,  // [H]
    const float4* __restrict__ meta, // [H]
    const float* __restrict__ h0g,   // [B, H]
    unsigned long long* __restrict__ flags, // [B][NSTRIP][NCH][NB] {flag|val}
    float* __restrict__ out) {       // [B*T, H]
  __shared__ __align__(16) __bf16 As[2][4][TCH][8];  // 16 KB [buf][kq][row^kq][8]
  __shared__ __align__(16) __bf16 Bs[3][4][NB][8];   // 24 KB [buf][kq][col][8]
  // scan scratch aliased into As (dead after the k-loop):
  // scr[0..255] = chunkTot[2][NB], scr[256..383] = colCarry[NB]
  float* const scr = (float*)&As[0][0][0][0];

  const int tid  = threadIdx.x;
  const int wave = tid >> 6;
  const int lane = tid & 63;
  const int q  = lane >> 4;      // 0..3
  const int c  = lane & 15;      // 0..15
  const int rw = wave & 1;       // row half: rows rw*64..+64
  const int cg = wave >> 1;      // col half: cols cg*64..+64

  const int bid   = blockIdx.x;
  const int g     = bid & 127;
  const int strip = bid >> 7;    // 0..7
  const int b     = g >> 3;
  const int chunk = g & 7;
  const int t0    = chunk * TCH;
  const int n0    = strip * NB;

  const int arow  = tid >> 1;    // 0..127: this thread's A row
  const int khalf = tid & 1;     // which 16-float half of the 32-k window

  float bias_j[4];
#pragma unroll
  for (int j = 0; j < 4; ++j) bias_j[j] = bias[n0 + cg * 64 + j * 16 + c];

  const float* const xR = xf + (size_t)(b * T_DIM + t0 + arow) * DK + khalf * 16;

  // ---- A: reg-staged.  loadA(kt): 4x f32x4, 64B row-contiguous per thread.
  f32x4 ar[4];
  auto loadA = [&](int kt) {
#pragma unroll
    for (int it = 0; it < 4; ++it)
      ar[it] = *(const f32x4*)(xR + kt * 32 + it * 4);
  };
  // writeA: cvt 16 f32 -> 2 bf16x8 octets, swizzled ds_write_b128 (XOR row^kq)
  auto writeA = [&](int buf) {
#pragma unroll
    for (int o = 0; o < 2; ++o) {
      const int kq = khalf * 2 + o;
      bf16x8 t;
      t[0] = (__bf16)ar[o * 2].x; t[1] = (__bf16)ar[o * 2].y;
      t[2] = (__bf16)ar[o * 2].z; t[3] = (__bf16)ar[o * 2].w;
      t[4] = (__bf16)ar[o * 2 + 1].x; t[5] = (__bf16)ar[o * 2 + 1].y;
      t[6] = (__bf16)ar[o * 2 + 1].z; t[7] = (__bf16)ar[o * 2 + 1].w;
      *(bf16x8*)(&As[buf][kq][arow ^ kq][0]) = t;
    }
  };
  // ---- B: global_load_lds, 2 cp16/thread/tile
  auto stageB = [&](int kt) {
    const int buf = kt % 3;
#pragma unroll
    for (int it = 0; it < 2; ++it) {
      const int s = it * 256 + tid;
      const int kq = s >> 7, col = s & 127;
      async_cp16(wbT + ((size_t)(kt * 4 + kq) * H_DIM + n0 + col) * 8,
                 &Bs[buf][kq][col][0]);
    }
  };

  // bias folded into the MFMA C-init
  f32x4 acc[4][4];
#pragma unroll
  for (int i = 0; i < 4; ++i)
#pragma unroll
    for (int j = 0; j < 4; ++j)
      acc[i][j] = (f32x4){bias_j[j], bias_j[j], bias_j[j], bias_j[j]};

  // prologue: A(0) loaded+written; B(0),B(1) staged.
  // writeA(0)'s implicit wait = vmcnt(4) (loadA(0) oldest) -> sB(0),sB(1) stay.
  loadA(0);
  stageB(0); stageB(1);
  writeA(0);

  for (int kt = 0; kt < NKT; ++kt) {
    const int bufA = kt & 1, bufB = kt % 3;
    // ledger @bar1(kt): only stageB(kt+1)[2] may be outstanding (writeA(kt)
    // at end of kt-1 drained loadA(kt) and everything older, incl. B(kt)).
    asm volatile("s_waitcnt vmcnt(2)" ::: "memory");
    asm volatile("s_waitcnt lgkmcnt(0)" ::: "memory");  // A ds_writes visible
    __builtin_amdgcn_sched_barrier(0);
    __builtin_amdgcn_s_barrier();        // bar1: A(kt), B(kt) ready
    __builtin_amdgcn_sched_barrier(0);
    if (kt + 1 < NKT) loadA(kt + 1);     // issue early; hidden under MFMAs

    bf16x8 af[4];
#pragma unroll
    for (int i = 0; i < 4; ++i)
      af[i] = *(const bf16x8*)(&As[bufA][q][(rw * 64 + i * 16 + c) ^ q][0]);
    bf16x8 b0 = *(const bf16x8*)(&Bs[bufB][q][cg * 64 + 0 * 16 + c][0]);
    bf16x8 b1 = *(const bf16x8*)(&Bs[bufB][q][cg * 64 + 1 * 16 + c][0]);
#pragma unroll
    for (int i = 0; i < 4; ++i) {
      acc[i][0] = __builtin_amdgcn_mfma_f32_16x16x32_bf16(af[i], b0, acc[i][0], 0, 0, 0);
      acc[i][1] = __builtin_amdgcn_mfma_f32_16x16x32_bf16(af[i], b1, acc[i][1], 0, 0, 0);
    }
    bf16x8 b2 = *(const bf16x8*)(&Bs[bufB][q][cg * 64 + 2 * 16 + c][0]);
    bf16x8 b3 = *(const bf16x8*)(&Bs[bufB][q][cg * 64 + 3 * 16 + c][0]);
#pragma unroll
    for (int i = 0; i < 4; ++i) {
      acc[i][2] = __builtin_amdgcn_mfma_f32_16x16x32_bf16(af[i], b2, acc[i][2], 0, 0, 0);
      acc[i][3] = __builtin_amdgcn_mfma_f32_16x16x32_bf16(af[i], b3, acc[i][3], 0, 0, 0);
    }
    __builtin_amdgcn_sched_barrier(0);   // no LDS read may sink below
    __builtin_amdgcn_s_barrier();        // bar2: all reads of bufA/bufB done
    __builtin_amdgcn_sched_barrier(0);   // no restage may hoist above
    if (kt + 2 < NKT) stageB(kt + 2);    // -> Bs[(kt+2)%3], freed at kt-1
    if (kt + 1 < NKT) writeA(bufA ^ 1);  // -> As[(kt+1)&1], freed at kt-1;
                                         //    implicit wait drains loadA(kt+1)
  }

  // per-column constants for the scan (loaded post-loop: short live range)
  float la2_j[4], a_j[4], ai_j[4], sgn_j[4], h0_j[4];
  bool zm_j[4];
#pragma unroll
  for (int j = 0; j < 4; ++j) {
    const int col = n0 + cg * 64 + j * 16 + c;
    const float4 mt = meta[col];
    a_j[j]   = mt.x;
    la2_j[j] = mt.y;
    ai_j[j]  = 1.f / mt.x;              // signed 1/a (inf for a~0: handled)
    sgn_j[j] = (mt.z != 0.f) ? -1.f : 1.f;
    zm_j[j]  = mt.w != 0.f;
    h0_j[j]  = h0g[(size_t)b * H_DIM + col];
  }

  // ---- scan phase 1: per-wave weighted prefix over this wave's 64 rows ----
  // acc[i][j][r] = z (incl. bias) at t = t0+rw*64+i*16+q*4+r, col = n0+cg*64+j*16+c.
  // tp1 = t+1 is ODD at r=0, so sign of a^(t+1) at r=0 is sgn; multiplying by
  // signed 1/a alternates it.  inv = (u<0) ? 1e12 : min(u,1e12) reproduces
  // ref's 1/max(p,1e-12) exactly (incl. a<0 and a~0 cases).
  float base_[4][4];
  float icarry[4] = {0.f, 0.f, 0.f, 0.f};
#pragma unroll
  for (int i = 0; i < 4; ++i) {
    const int tp10 = t0 + rw * 64 + i * 16 + q * 4 + 1;
#pragma unroll
    for (int j = 0; j < 4; ++j) {
      float u = __builtin_amdgcn_exp2f(-la2_j[j] * (float)tp10) * sgn_j[j];
      f32x4 wv;
#pragma unroll
      for (int r = 0; r < 4; ++r) {
        const float uu = fminf(u, 1e12f);
        const float inv = (u < 0.f) ? 1e12f : uu;
        wv[r] = acc[i][j][r] * inv;
        u *= ai_j[j];
      }
      const float pr0 = wv[0];
      const float pr1 = pr0 + wv[1];
      const float pr2 = pr1 + wv[2];
      const float pr3 = pr2 + wv[3];
      const float x1 = __shfl_xor(pr3, 16, 64);   // q^1
      const float x2 = __shfl_xor(pr3, 32, 64);   // q^2
      const float x3 = __shfl_xor(pr3, 48, 64);   // q^3
      float sq = 0.f;
      if (q >= 2) sq += x2 + x3;
      if (q & 1) sq += x1;
      const float base = icarry[j] + sq;
      base_[i][j] = base;
      acc[i][j] = (f32x4){base + pr0, base + pr1, base + pr2, base + pr3};
      icarry[j] += pr3 + x1 + x2 + x3;   // total over this i-group's 16 rows
    }
  }
  if (q == 0) {
#pragma unroll
    for (int j = 0; j < 4; ++j) scr[rw * NB + cg * 64 + j * 16 + c] = icarry[j];
  }
  __syncthreads();

  // ---- publish own chunk total, then decoupled lookback for the carry ----
  if (tid < NB) {
    const int col = tid;
    const size_t fb = ((size_t)b * NSTRIP + strip) * NCH * NB;
    const float tot = scr[col] + scr[NB + col];
    atomicExch(&flags[fb + (size_t)chunk * NB + col],
               (1ULL << 32) | (unsigned long long)__float_as_uint(tot));
    float s = 0.f;
    for (int p = 0; p < chunk; ++p) {
      unsigned long long v = atomicAdd(&flags[fb + (size_t)p * NB + col], 0ULL);
      while (!(v >> 32)) {
        __builtin_amdgcn_s_sleep(4);
        v = atomicAdd(&flags[fb + (size_t)p * NB + col], 0ULL);
      }
      s += __uint_as_float((unsigned int)v);
    }
    scr[2 * NB + col] = s;
  }
  __syncthreads();

  // ---- phase 2: add carry (+h0), produce h = p*(v+h0), write out ----
  float cc_[4];
#pragma unroll
  for (int j = 0; j < 4; ++j) {
    const int colL = cg * 64 + j * 16 + c;
    float s = scr[2 * NB + colL];
    if (rw) s += scr[colL];
    cc_[j] = s + h0_j[j];
  }
#pragma unroll
  for (int i = 0; i < 4; ++i) {
    const int tp10 = t0 + rw * 64 + i * 16 + q * 4 + 1;
#pragma unroll
    for (int j = 0; j < 4; ++j) {
      float pv = __builtin_amdgcn_exp2f(la2_j[j] * (float)tp10) * sgn_j[j];
      const int col = n0 + cg * 64 + j * 16 + c;
#pragma unroll
      for (int r = 0; r < 4; ++r) {
        const int tl = t0 + rw * 64 + i * 16 + q * 4 + r;
        const float hv = pv * (acc[i][j][r] + cc_[j]);
        // zero-mask path: recover z = w*1e-12 (inv == 1e12 exactly when zm)
        const float wr = acc[i][j][r] - ((r == 0) ? base_[i][j] : acc[i][j][r - 1]);
        out[(size_t)(b * T_DIM + tl) * H_DIM + col] = zm_j[j] ? wr * 1e-12f : hv;
        pv *= a_j[j];
      }
    }
  }
}

extern "C" void kernel_launch(void* const* d_in, const int* in_sizes, int n_in,
                              void* d_out, int out_size, void* d_ws, size_t ws_size,
                              hipStream_t stream) {
  const float* x     = (const float*)d_in[0];  // [B,T,DK]
  const float* h0    = (const float*)d_in[1];  // [B,H]
  const float* raw_a = (const float*)d_in[2];  // [H]
  const float* W     = (const float*)d_in[3];  // [H,DK]
  const float* bias  = (const float*)d_in[4];  // [H]
  float* out = (float*)d_out;                  // [B,T,H]

  char* ws = (char*)d_ws;
  __bf16* wbT = (__bf16*)(ws);                         // 1048576 B
  float4* meta = (float4*)(ws + 1048576);              //   16384 B
  unsigned long long* flags =
      (unsigned long long*)(ws + 1048576 + 16384);     // 1048576 B

  prep<<<1028, 256, 0, stream>>>(W, wbT, raw_a, meta, flags);
  fused_rnn<<<1024, 256, 0, stream>>>(x, wbT, bias, meta, h0, flags, out);
}

// Round 12
// 123.418 us; speedup vs baseline: 1.1502x; 1.1502x over previous
//
#include <hip/hip_runtime.h>
#include <cstdint>

// Problem dims (fixed by the reference)
#define B_DIM 16
#define T_DIM 1024
#define DK    512     // D_IN
#define H_DIM 1024

// Tiling
#define TCH    128                 // t-rows per block (chunk)
#define NCH    (T_DIM / TCH)       // 8 chunks per (b,strip)
#define NB     128                 // output cols per block
#define NSTRIP (H_DIM / NB)        // 8 strips
#define NKT    16                  // k-tiles of BK=32
#define BKQ    4                   // 16B k-chunks per k-tile

typedef __bf16 bf16x8 __attribute__((ext_vector_type(8)));
typedef __bf16 bf16x4 __attribute__((ext_vector_type(4)));
typedef float  f32x4  __attribute__((ext_vector_type(4)));

// ---- async global->LDS (16B per lane, wave-uniform LDS base + lane*16) ----
typedef __attribute__((address_space(1))) unsigned int* as1p;
typedef __attribute__((address_space(3))) unsigned int* as3p;

__device__ __forceinline__ void async_cp16(const void* g, void* l) {
  __builtin_amdgcn_global_load_lds((as1p)(uint64_t)g,
                                   (as3p)(uint32_t)(uint64_t)l, 16, 0, 0);
}

// ---- merged prep (r3-proven, byte-identical) ----
// x: f32 [B][T][DK] -> bf16 k-major xbt[b][kq=0..63][t=0..1023][8]
// W: f32 [H][DK]    -> bf16 k-major wbT[kq][h][8]
// meta: {a, log2|a|, neg?, zero?} per h;  flags: zeroed lookback array.
// grid = 4096 (x) + 512 (W) + 4 (meta) + 512 (flags) = 5124 blocks x 256 thr
__global__ __launch_bounds__(256) void prep(const float* __restrict__ x,
                                            __bf16* __restrict__ xbt,
                                            const float* __restrict__ W,
                                            __bf16* __restrict__ wbT,
                                            const float* __restrict__ raw_a,
                                            float4* __restrict__ meta,
                                            unsigned long long* __restrict__ flags) {
  const int bid = blockIdx.x, tid = threadIdx.x;
  if (bid < 4096) {                       // x transpose + cvt, 8 elems/thread
    const int g = bid * 256 + tid;        // < 1048576
    const int b = g >> 16;
    const int r = g & 65535;
    // 4 lanes share a 128B x-row segment (coalesced reads);
    // 16 lanes of one kq write 256B contiguous in xbt (coalesced writes).
    const int kq = ((r >> 12) << 2) | (tid & 3);                // 0..63
    const int t  = (((r >> 6) & 63) << 4) | ((tid & 63) >> 2);  // 0..1023
    const float* src = x + ((size_t)(b * T_DIM + t) * DK + kq * 8);
    f32x4 v0 = ((const f32x4*)src)[0];
    f32x4 v1 = ((const f32x4*)src)[1];
    bf16x8 o;
    o[0] = (__bf16)v0.x; o[1] = (__bf16)v0.y; o[2] = (__bf16)v0.z; o[3] = (__bf16)v0.w;
    o[4] = (__bf16)v1.x; o[5] = (__bf16)v1.y; o[6] = (__bf16)v1.z; o[7] = (__bf16)v1.w;
    *(bf16x8*)(xbt + ((size_t)(b * 64 + kq) * T_DIM + t) * 8) = o;
  } else if (bid < 4608) {                // W -> wbT[kq][h][8]
    const int i = (bid - 4096) * 256 + tid;   // i < 131072
    const int h  = i >> 7;                // DK/4 = 128 x4-chunks per row
    const int k0 = (i & 127) * 4;
    f32x4 v = ((const f32x4*)W)[i];
    bf16x4 o;
    o.x = (__bf16)v.x; o.y = (__bf16)v.y; o.z = (__bf16)v.z; o.w = (__bf16)v.w;
    *(bf16x4*)(wbT + ((size_t)(k0 >> 3) * H_DIM + h) * 8 + (k0 & 7)) = o;
  } else if (bid < 4612) {                // meta
    const int h = (bid - 4608) * 256 + tid;
    const float a = tanhf(raw_a[h]);
    const float la2 = log2f(fabsf(a));
    meta[h] = make_float4(a, la2, (a < 0.f) ? 1.f : 0.f, (fabsf(a) < 1e-6f) ? 1.f : 0.f);
  } else {                                // lookback flags: zero 131072 u64
    flags[(bid - 4612) * 256 + tid] = 0ULL;
  }
}

// ---- fused: GEMM (z = x W^T + b) + chunk-parallel weighted-cumsum scan ----
// = the proven 124.3µs r3 kernel with ONE edit: lookback polls use
// __hip_atomic_load (relaxed, AGENT scope) instead of atomicAdd(p,0).
// A pure load dirties no lines -> kills the ~39MB/launch of spurious RMW
// writeback traffic (r8-r10 counters).  Correctness: {flag|payload} live in
// ONE 64-bit word (no tearing, no ordering needed); publish stays the
// device-scope atomicExch.  The k-loop is byte-identical to r3: depth-3,
// vmcnt(8/4/0), TWO barriers per k-step with sched_barrier(0) pinning the
// MFMA cluster above bar2 (r11's single-barrier variant failed: MFMAs sink
// past barriers unless pinned — rule #18).
// Grid: 1024 blocks; g = bid&127 (b = g>>3, chunk = g&7), strip = bid>>7.
// bid%8 == chunk pins each (b,chunk) x-panel to one XCD's L2; lookback
// predecessors are within 7 adjacent bids (dispatch-order safe, co-resident).
__global__ __launch_bounds__(256, 3) void fused_rnn(
    const __bf16* __restrict__ xbt,  // [B][64][T][8] k-major
    const __bf16* __restrict__ wbT,  // [64][H][8]   k-major
    const float* __restrict__ bias,  // [H]
    const float4* __restrict__ meta, // [H]
    const float* __restrict__ h0g,   // [B, H]
    unsigned long long* __restrict__ flags, // [B][NSTRIP][NCH][NB] {flag|val}
    float* __restrict__ out) {       // [B*T, H]
  __shared__ __align__(16) __bf16 As[3][BKQ][TCH][8];  // 24 KB
  __shared__ __align__(16) __bf16 Bs[3][BKQ][NB][8];   // 24 KB
  __shared__ float chunkTot[2][NB];
  __shared__ float colCarry[NB];

  const int tid  = threadIdx.x;
  const int wave = tid >> 6;
  const int lane = tid & 63;
  const int q  = lane >> 4;      // 0..3
  const int c  = lane & 15;      // 0..15
  const int rw = wave & 1;       // row half: rows rw*64..+64
  const int cg = wave >> 1;      // col half: cols cg*64..+64

  const int bid   = blockIdx.x;
  const int g     = bid & 127;
  const int strip = bid >> 7;    // 0..7
  const int b     = g >> 3;
  const int chunk = g & 7;
  const int t0    = chunk * TCH;
  const int n0    = strip * NB;

  // per-lane column constants (4 cols per lane: cg*64 + j*16 + c)
  float bias_j[4], la2_j[4], a_j[4], ai_j[4], sgn_j[4], h0_j[4];
  bool zm_j[4];
#pragma unroll
  for (int j = 0; j < 4; ++j) {
    const int col = n0 + cg * 64 + j * 16 + c;
    bias_j[j] = bias[col];
    const float4 mt = meta[col];
    a_j[j]   = mt.x;
    la2_j[j] = mt.y;
    ai_j[j]  = 1.f / mt.x;              // signed 1/a (inf for a~0: handled)
    sgn_j[j] = (mt.z != 0.f) ? -1.f : 1.f;
    zm_j[j]  = mt.w != 0.f;
    h0_j[j]  = h0g[(size_t)b * H_DIM + col];
  }

  // stage one BK=32 k-tile (A: 512 slots, B: 512 slots -> 4 cp16/thread);
  // vmcnt counts below depend on 4 loads/thread/tile
  auto stage = [&](int kt, int buf) {
    const int kq0 = kt * BKQ;
#pragma unroll
    for (int it = 0; it < 2; ++it) {
      const int s = it * 256 + tid;
      const int kq = s >> 7, row = s & 127;
      async_cp16(xbt + ((size_t)(b * 64 + kq0 + kq) * T_DIM + t0 + row) * 8,
                 &As[buf][kq][row][0]);
    }
#pragma unroll
    for (int it = 0; it < 2; ++it) {
      const int s = it * 256 + tid;
      const int kq = s >> 7, col = s & 127;
      async_cp16(wbT + ((size_t)(kq0 + kq) * H_DIM + n0 + col) * 8,
                 &Bs[buf][kq][col][0]);
    }
  };

  // bias folded into the MFMA C-init (all 4 rows of a frag share the column)
  f32x4 acc[4][4];
#pragma unroll
  for (int i = 0; i < 4; ++i)
#pragma unroll
    for (int j = 0; j < 4; ++j)
      acc[i][j] = (f32x4){bias_j[j], bias_j[j], bias_j[j], bias_j[j]};

  // prologue: 3 tiles in flight
  stage(0, 0); stage(1, 1); stage(2, 2);

  int buf = 0;
  for (int kt = 0; kt < NKT; ++kt) {
    // wait for tile kt only; later tiles' loads stay in flight (4 loads/tile)
    if (kt < NKT - 2)       asm volatile("s_waitcnt vmcnt(8)" ::: "memory");
    else if (kt == NKT - 2) asm volatile("s_waitcnt vmcnt(4)" ::: "memory");
    else                    asm volatile("s_waitcnt vmcnt(0)" ::: "memory");
    __builtin_amdgcn_s_barrier();   // tile-kt loads visible to all waves;
                                    // everyone also done reading buf (kt-3)
    bf16x8 af[4], bfr[4];
#pragma unroll
    for (int i = 0; i < 4; ++i)
      af[i] = *(const bf16x8*)(&As[buf][q][rw * 64 + i * 16 + c][0]);
#pragma unroll
    for (int j = 0; j < 4; ++j)
      bfr[j] = *(const bf16x8*)(&Bs[buf][q][cg * 64 + j * 16 + c][0]);
#pragma unroll
    for (int i = 0; i < 4; ++i)
#pragma unroll
      for (int j = 0; j < 4; ++j)
        acc[i][j] = __builtin_amdgcn_mfma_f32_16x16x32_bf16(af[i], bfr[j], acc[i][j], 0, 0, 0);
    __builtin_amdgcn_sched_barrier(0);  // pin ds_reads+MFMAs above bar2
    __builtin_amdgcn_s_barrier();       // all reads of buf done -> restage ok
    if (kt < NKT - 3) stage(kt + 3, buf);
    buf = (buf == 2) ? 0 : buf + 1;
  }

  // ---- scan phase 1: per-wave weighted prefix over this wave's 64 rows ----
  // acc[i][j][r] = z (incl. bias) at t = t0+rw*64+i*16+q*4+r, col = n0+cg*64+j*16+c.
  // tp1 = t+1 is ODD at r=0, so sign of a^(t+1) at r=0 is sgn; multiplying by
  // signed 1/a alternates it.  inv = (u<0) ? 1e12 : min(u,1e12) reproduces
  // ref's 1/max(p,1e-12) exactly (incl. a<0 and a~0 cases).
  float base_[4][4];
  float icarry[4] = {0.f, 0.f, 0.f, 0.f};
#pragma unroll
  for (int i = 0; i < 4; ++i) {
    const int tp10 = t0 + rw * 64 + i * 16 + q * 4 + 1;
#pragma unroll
    for (int j = 0; j < 4; ++j) {
      float u = __builtin_amdgcn_exp2f(-la2_j[j] * (float)tp10) * sgn_j[j];
      f32x4 wv;
#pragma unroll
      for (int r = 0; r < 4; ++r) {
        const float uu = fminf(u, 1e12f);
        const float inv = (u < 0.f) ? 1e12f : uu;
        wv[r] = acc[i][j][r] * inv;
        u *= ai_j[j];
      }
      const float pr0 = wv[0];
      const float pr1 = pr0 + wv[1];
      const float pr2 = pr1 + wv[2];
      const float pr3 = pr2 + wv[3];
      const float x1 = __shfl_xor(pr3, 16, 64);   // q^1
      const float x2 = __shfl_xor(pr3, 32, 64);   // q^2
      const float x3 = __shfl_xor(pr3, 48, 64);   // q^3
      float sq = 0.f;
      if (q >= 2) sq += x2 + x3;
      if (q & 1) sq += x1;
      const float base = icarry[j] + sq;
      base_[i][j] = base;
      acc[i][j] = (f32x4){base + pr0, base + pr1, base + pr2, base + pr3};
      icarry[j] += pr3 + x1 + x2 + x3;   // total over this i-group's 16 rows
    }
  }
  if (q == 0) {
#pragma unroll
    for (int j = 0; j < 4; ++j) chunkTot[rw][cg * 64 + j * 16 + c] = icarry[j];
  }
  __syncthreads();

  // ---- publish own chunk total, then decoupled lookback for the carry ----
  if (tid < NB) {
    const int col = tid;
    const size_t fb = ((size_t)b * NSTRIP + strip) * NCH * NB;
    const float tot = chunkTot[0][col] + chunkTot[1][col];
    atomicExch(&flags[fb + (size_t)chunk * NB + col],
               (1ULL << 32) | (unsigned long long)__float_as_uint(tot));
    float s = 0.f;
    for (int p = 0; p < chunk; ++p) {
      unsigned long long v = __hip_atomic_load(
          &flags[fb + (size_t)p * NB + col],
          __ATOMIC_RELAXED, __HIP_MEMORY_SCOPE_AGENT);
      while (!(v >> 32)) {
        __builtin_amdgcn_s_sleep(4);
        v = __hip_atomic_load(&flags[fb + (size_t)p * NB + col],
                              __ATOMIC_RELAXED, __HIP_MEMORY_SCOPE_AGENT);
      }
      s += __uint_as_float((unsigned int)v);
    }
    colCarry[col] = s;
  }
  __syncthreads();

  // ---- phase 2: add carry (+h0), produce h = p*(v+h0), write out ----
  float cc_[4];
#pragma unroll
  for (int j = 0; j < 4; ++j) {
    const int colL = cg * 64 + j * 16 + c;
    float s = colCarry[colL];
    if (rw) s += chunkTot[0][colL];
    cc_[j] = s + h0_j[j];
  }
#pragma unroll
  for (int i = 0; i < 4; ++i) {
    const int tp10 = t0 + rw * 64 + i * 16 + q * 4 + 1;
#pragma unroll
    for (int j = 0; j < 4; ++j) {
      float pv = __builtin_amdgcn_exp2f(la2_j[j] * (float)tp10) * sgn_j[j];
      const int col = n0 + cg * 64 + j * 16 + c;
#pragma unroll
      for (int r = 0; r < 4; ++r) {
        const int tl = t0 + rw * 64 + i * 16 + q * 4 + r;
        const float hv = pv * (acc[i][j][r] + cc_[j]);
        // zero-mask path: recover z = w*1e-12 (inv == 1e12 exactly when zm)
        const float wr = acc[i][j][r] - ((r == 0) ? base_[i][j] : acc[i][j][r - 1]);
        out[(size_t)(b * T_DIM + tl) * H_DIM + col] = zm_j[j] ? wr * 1e-12f : hv;
        pv *= a_j[j];
      }
    }
  }
}

extern "C" void kernel_launch(void* const* d_in, const int* in_sizes, int n_in,
                              void* d_out, int out_size, void* d_ws, size_t ws_size,
                              hipStream_t stream) {
  const float* x     = (const float*)d_in[0];  // [B,T,DK]
  const float* h0    = (const float*)d_in[1];  // [B,H]
  const float* raw_a = (const float*)d_in[2];  // [H]
  const float* W     = (const float*)d_in[3];  // [H,DK]
  const float* bias  = (const float*)d_in[4];  // [H]
  float* out = (float*)d_out;                  // [B,T,H]

  char* ws = (char*)d_ws;
  __bf16* xbt = (__bf16*)(ws);                               // 16777216 B
  __bf16* wbT = (__bf16*)(ws + 16777216);                    //  1048576 B
  float4* meta = (float4*)(ws + 16777216 + 1048576);         //    16384 B
  unsigned long long* flags =
      (unsigned long long*)(ws + 16777216 + 1048576 + 16384); // 1048576 B

  prep<<<5124, 256, 0, stream>>>(x, xbt, W, wbT, raw_a, meta, flags);
  fused_rnn<<<1024, 256, 0, stream>>>(xbt, wbT, bias, meta, h0, flags, out);
}